// Round 1
// baseline (722.970 us; speedup 1.0000x reference)
//
#include <hip/hip_runtime.h>
#include <hip/hip_bf16.h>
#include <math.h>

#define NQ 300
#define BSZ 8
#define DIM 256
#define NHEAD 8
#define ROWS (NQ * BSZ)  // 2400

// ---------------- elementwise add (float4) ----------------
__global__ __launch_bounds__(256) void add4_kernel(const float4* __restrict__ a,
                                                   const float4* __restrict__ b,
                                                   float4* __restrict__ o, int n4) {
  int i = blockIdx.x * 256 + threadIdx.x;
  if (i < n4) {
    float4 x = a[i], y = b[i];
    o[i] = make_float4(x.x + y.x, x.y + y.y, x.z + y.z, x.w + y.w);
  }
}

// ---------------- generic tiled fp32 GEMM: C[M][N] = A[M][K] @ W[N][K]^T + bias ----------------
// Optional RELU epilogue; optional VMASK (zero rows where key_padding_mask true; rows are s*8+b).
template <int BM, int BN, int BK, int TM, int TN, bool RELU, bool VMASK>
__global__ __launch_bounds__(256) void gemm_kernel(const float* __restrict__ A,
                                                   const float* __restrict__ W,
                                                   const float* __restrict__ bias,
                                                   float* __restrict__ C, int M, int N, int K,
                                                   const unsigned char* __restrict__ vmask,
                                                   int Srows) {
  static_assert((BM / TM) * (BN / TN) == 256, "need 256 threads");
  __shared__ float As[BK][BM];
  __shared__ float Bs[BK][BN];
  const int tid = threadIdx.x;
  const int m0 = blockIdx.x * BM;
  const int n0 = blockIdx.y * BN;
  constexpr int CT = BN / TN;
  const int tx = tid % CT;
  const int ty = tid / CT;
  constexpr int A_F4 = BM * BK / 1024;  // float4 loads per thread for A tile
  constexpr int W_F4 = BN * BK / 1024;
  constexpr int KC = BK / 4;

  float acc[TM][TN];
#pragma unroll
  for (int i = 0; i < TM; ++i)
#pragma unroll
    for (int j = 0; j < TN; ++j) acc[i][j] = 0.f;

  for (int k0 = 0; k0 < K; k0 += BK) {
    __syncthreads();
#pragma unroll
    for (int i = 0; i < A_F4; ++i) {
      int t = tid + i * 256;
      int row = t / KC;
      int kc = (t % KC) * 4;
      float4 v = make_float4(0.f, 0.f, 0.f, 0.f);
      int gr = m0 + row;
      if (gr < M) v = *(const float4*)&A[(size_t)gr * K + k0 + kc];
      As[kc + 0][row] = v.x;
      As[kc + 1][row] = v.y;
      As[kc + 2][row] = v.z;
      As[kc + 3][row] = v.w;
    }
#pragma unroll
    for (int i = 0; i < W_F4; ++i) {
      int t = tid + i * 256;
      int row = t / KC;
      int kc = (t % KC) * 4;
      float4 v = make_float4(0.f, 0.f, 0.f, 0.f);
      int gc = n0 + row;
      if (gc < N) v = *(const float4*)&W[(size_t)gc * K + k0 + kc];
      Bs[kc + 0][row] = v.x;
      Bs[kc + 1][row] = v.y;
      Bs[kc + 2][row] = v.z;
      Bs[kc + 3][row] = v.w;
    }
    __syncthreads();
#pragma unroll
    for (int kk = 0; kk < BK; ++kk) {
      float a[TM], w[TN];
#pragma unroll
      for (int i = 0; i < TM; i += 4) *(float4*)&a[i] = *(const float4*)&As[kk][ty * TM + i];
#pragma unroll
      for (int j = 0; j < TN; j += 4) *(float4*)&w[j] = *(const float4*)&Bs[kk][tx * TN + j];
#pragma unroll
      for (int i = 0; i < TM; ++i)
#pragma unroll
        for (int j = 0; j < TN; ++j) acc[i][j] = fmaf(a[i], w[j], acc[i][j]);
    }
  }

#pragma unroll
  for (int i = 0; i < TM; ++i) {
    int gr = m0 + ty * TM + i;
    if (gr >= M) continue;
    float mfac = 1.f;
    if (VMASK) mfac = vmask[(size_t)(gr & 7) * Srows + (gr >> 3)] ? 0.f : 1.f;
#pragma unroll
    for (int j = 0; j < TN; j += 4) {
      int gc = n0 + tx * TN + j;
      float4 b4 = *(const float4*)&bias[gc];
      float4 ov;
      ov.x = acc[i][j + 0] + b4.x;
      ov.y = acc[i][j + 1] + b4.y;
      ov.z = acc[i][j + 2] + b4.z;
      ov.w = acc[i][j + 3] + b4.w;
      if (VMASK) {
        ov.x *= mfac; ov.y *= mfac; ov.z *= mfac; ov.w *= mfac;
      }
      if (RELU) {
        ov.x = fmaxf(ov.x, 0.f); ov.y = fmaxf(ov.y, 0.f);
        ov.z = fmaxf(ov.z, 0.f); ov.w = fmaxf(ov.w, 0.f);
      }
      *(float4*)&C[(size_t)gr * N + gc] = ov;
    }
  }
}

// ---------------- self-attention, flash-style ----------------
// block = (b, h, qtile of 64 rows); thread = (row_local, quarter of head dim)
// cqk rows (q*8+b): cols [0:256)=qh, [256:512)=kh ; cv rows: vh cols [0:256)
__global__ __launch_bounds__(256) void attn_kernel(const float* __restrict__ cqk,
                                                   const float* __restrict__ cv,
                                                   float* __restrict__ out) {
  __shared__ float Ks[NQ][32];
  __shared__ float Vs[NQ][32];
  const int b = blockIdx.x, h = blockIdx.y, qt = blockIdx.z;
  const int tid = threadIdx.x;
  for (int i = tid; i < NQ * 8; i += 256) {
    int qi = i >> 3, c4 = (i & 7) * 4;
    *(float4*)&Ks[qi][c4] = *(const float4*)&cqk[((size_t)(qi * 8 + b)) * 512 + 256 + h * 32 + c4];
    *(float4*)&Vs[qi][c4] = *(const float4*)&cv[((size_t)(qi * 8 + b)) * 256 + h * 32 + c4];
  }
  __syncthreads();
  const int row = qt * 64 + (tid >> 2);
  const int qr = tid & 3;  // quarter of the 32-dim head
  if (row >= NQ) return;
  float qv[8];
  const float* qptr = &cqk[((size_t)(row * 8 + b)) * 512 + h * 32 + qr * 8];
  *(float4*)&qv[0] = *(const float4*)&qptr[0];
  *(float4*)&qv[4] = *(const float4*)&qptr[4];
  const float scale = 0.17677669529663687f;  // 1/sqrt(32)
  float m = -3.0e38f, l = 0.f;
  float acc[8] = {0.f, 0.f, 0.f, 0.f, 0.f, 0.f, 0.f, 0.f};
  for (int k = 0; k < NQ; ++k) {
    const float* kr = &Ks[k][qr * 8];
    float p = 0.f;
#pragma unroll
    for (int j = 0; j < 8; ++j) p = fmaf(qv[j], kr[j], p);
    p += __shfl_xor(p, 1, 4);
    p += __shfl_xor(p, 2, 4);
    float s = p * scale;
    float mn = fmaxf(m, s);
    float corr = __expf(m - mn);
    float e = __expf(s - mn);
    l = l * corr + e;
    const float* vr = &Vs[k][qr * 8];
#pragma unroll
    for (int j = 0; j < 8; ++j) acc[j] = fmaf(acc[j], corr, e * vr[j]);
    m = mn;
  }
  float inv = 1.f / l;
  float* op = &out[((size_t)(row * 8 + b)) * 256 + h * 32 + qr * 8];
#pragma unroll
  for (int j = 0; j < 8; ++j) op[j] = acc[j] * inv;
}

// ---------------- residual + layernorm (row = (q,b), 256 cols) ----------------
// out = LN(X + R); optionally out2 = out + addmask
__global__ __launch_bounds__(256) void resid_ln_kernel(const float* __restrict__ X,
                                                       const float* __restrict__ R,
                                                       const float* __restrict__ g,
                                                       const float* __restrict__ be,
                                                       const float* __restrict__ addmask,
                                                       float* __restrict__ out,
                                                       float* __restrict__ out2) {
  const int r = blockIdx.x, c = threadIdx.x;
  const size_t i = (size_t)r * 256 + c;
  float x = X[i] + R[i];
  float s = x;
#pragma unroll
  for (int o = 32; o; o >>= 1) s += __shfl_xor(s, o, 64);
  __shared__ float sm[4], sv[4];
  const int w = c >> 6;
  if ((c & 63) == 0) sm[w] = s;
  __syncthreads();
  float mu = (sm[0] + sm[1] + sm[2] + sm[3]) * (1.f / 256.f);
  float d = x - mu;
  float v = d * d;
#pragma unroll
  for (int o = 32; o; o >>= 1) v += __shfl_xor(v, o, 64);
  if ((c & 63) == 0) sv[w] = v;
  __syncthreads();
  float var = (sv[0] + sv[1] + sv[2] + sv[3]) * (1.f / 256.f);
  float y = d * (1.f / sqrtf(var + 1e-5f)) * g[c] + be[c];
  out[i] = y;
  if (out2) out2[i] = y + addmask[i];
}

// ---------------- multi-scale deformable sampling ----------------
// block = (q,b) row; thread = (h, d); aw softmax fused via 32-lane shuffles.
__global__ __launch_bounds__(256) void deform_kernel(const float* __restrict__ value,
                                                     const float* __restrict__ off,
                                                     const float* __restrict__ awl,
                                                     const float* __restrict__ bbox,
                                                     const int* __restrict__ spatial,
                                                     const int* __restrict__ lstart,
                                                     float* __restrict__ out, int S) {
  __shared__ int sH[4], sW[4], sL[4];
  __shared__ float sbb[4];
  const int r = blockIdx.x;  // q*8+b
  const int b = r & 7;
  const int tid = threadIdx.x;
  if (tid < 4) {
    sH[tid] = spatial[tid * 2];
    sW[tid] = spatial[tid * 2 + 1];
    sL[tid] = lstart[tid];
    sbb[tid] = bbox[(size_t)r * 4 + tid];
  }
  __syncthreads();
  const int h = tid >> 5;
  const int d = tid & 31;
  const float cx = sbb[0], cy = sbb[1], bw = sbb[2], bh = sbb[3];
  float ox = off[(size_t)r * 512 + (size_t)(h * 32 + d) * 2];
  float oy = off[(size_t)r * 512 + (size_t)(h * 32 + d) * 2 + 1];
  float a = awl[(size_t)r * 256 + h * 32 + d];
  // softmax over the 32 (level,point) logits of this head
  float mx = a;
#pragma unroll
  for (int o = 16; o; o >>= 1) mx = fmaxf(mx, __shfl_xor(mx, o, 32));
  float e = __expf(a - mx);
  float ssum = e;
#pragma unroll
  for (int o = 16; o; o >>= 1) ssum += __shfl_xor(ssum, o, 32);
  float myaw = e / ssum;

  float acc = 0.f;
  const size_t vb = (size_t)b * 256 + (size_t)tid;  // value[(idx*8+b)*256 + h*32 + d]
  for (int lp = 0; lp < 32; ++lp) {
    const int l = lp >> 3;
    float bx = __shfl(ox, lp, 32);
    float by = __shfl(oy, lp, 32);
    float alp = __shfl(myaw, lp, 32);
    const float Wf = (float)sW[l], Hf = (float)sH[l];
    const int ls = sL[l], Wi = sW[l];
    float lx = cx + bx * 0.0625f * bw;  // off/NP * w * 0.5 = off * 0.0625 * w
    float ly = cy + by * 0.0625f * bh;
    float x = lx * Wf - 0.5f;
    float y = ly * Hf - 0.5f;
    float x0 = floorf(x), y0 = floorf(y);
    float fx = x - x0, fy = y - y0;
    float tap = 0.f;
#pragma unroll
    for (int t = 0; t < 4; ++t) {
      float xi = x0 + (float)(t & 1);
      float yi = y0 + (float)(t >> 1);
      if (xi >= 0.f && yi >= 0.f && xi < Wf && yi < Hf) {
        float wx = (t & 1) ? fx : (1.f - fx);
        float wy = (t >> 1) ? fy : (1.f - fy);
        int idx = ls + (int)yi * Wi + (int)xi;
        tap = fmaf(wx * wy, value[(size_t)idx * 2048 + vb], tap);
      }
    }
    acc = fmaf(alp, tap, acc);
  }
  out[(size_t)r * 256 + tid] = acc;
}

extern "C" void kernel_launch(void* const* d_in, const int* in_sizes, int n_in, void* d_out,
                              int out_size, void* d_ws, size_t ws_size, hipStream_t stream) {
  (void)n_in; (void)out_size; (void)ws_size;
  const float* tgt = (const float*)d_in[0];
  const float* qmask = (const float*)d_in[1];
  const float* bbox = (const float*)d_in[2];
  const float* memory = (const float*)d_in[4];
  const float* ipw = (const float*)d_in[5];
  const float* ipb = (const float*)d_in[6];
  const float* osw = (const float*)d_in[7];
  const float* osb = (const float*)d_in[8];
  const float* n2g = (const float*)d_in[9];
  const float* n2b = (const float*)d_in[10];
  const float* vw = (const float*)d_in[11];
  const float* vbi = (const float*)d_in[12];
  const float* ow = (const float*)d_in[13];
  const float* ob = (const float*)d_in[14];
  const float* aww = (const float*)d_in[15];
  const float* awb = (const float*)d_in[16];
  const float* ocw = (const float*)d_in[17];
  const float* ocb = (const float*)d_in[18];
  const float* n1g = (const float*)d_in[19];
  const float* n1b = (const float*)d_in[20];
  const float* l1w = (const float*)d_in[21];
  const float* l1b = (const float*)d_in[22];
  const float* l2w = (const float*)d_in[23];
  const float* l2b = (const float*)d_in[24];
  const float* n3g = (const float*)d_in[25];
  const float* n3b = (const float*)d_in[26];
  const unsigned char* kpmask = (const unsigned char*)d_in[27];
  const int* spatial = (const int*)d_in[28];
  const int* lstart = (const int*)d_in[29];
  float* out = (float*)d_out;

  const int S = in_sizes[4] / (BSZ * DIM);  // 13294
  const int Mv = S * BSZ;                   // 106352

  float* ws = (float*)d_ws;
  size_t o = 0;
  float* value = ws + o; o += (size_t)Mv * DIM;   // 106352x256
  float* qsum = ws + o; o += (size_t)ROWS * DIM;  // tgt + query_mask
  float* cqk = ws + o; o += (size_t)ROWS * 512;   // qh|kh ; later off_out
  float* cv = ws + o; o += (size_t)ROWS * DIM;    // vh ; later aw_out
  float* sraw = ws + o; o += (size_t)ROWS * DIM;  // attn out ; later ca_pre
  float* proj = ws + o; o += (size_t)ROWS * DIM;  // sa/ca/ffn2 projection out
  float* tgt2 = ws + o; o += (size_t)ROWS * DIM;
  float* q2 = ws + o; o += (size_t)ROWS * DIM;
  float* tgt3 = ws + o; o += (size_t)ROWS * DIM;
  float* ffn1 = ws + o; o += (size_t)ROWS * 1024;

  // 1. qsum = tgt + query_mask
  add4_kernel<<<dim3((ROWS * DIM / 4 + 255) / 256), 256, 0, stream>>>(
      (const float4*)tgt, (const float4*)qmask, (float4*)qsum, ROWS * DIM / 4);
  // 2. q/k projection (N=512)
  gemm_kernel<64, 64, 16, 4, 4, false, false><<<dim3((ROWS + 63) / 64, 8), 256, 0, stream>>>(
      qsum, ipw, ipb, cqk, ROWS, 512, DIM, nullptr, 0);
  // 3. v projection (from tgt, rows 512..767 of in_proj)
  gemm_kernel<64, 64, 16, 4, 4, false, false><<<dim3((ROWS + 63) / 64, 4), 256, 0, stream>>>(
      tgt, ipw + 512 * DIM, ipb + 512, cv, ROWS, 256, DIM, nullptr, 0);
  // 4. self-attention
  attn_kernel<<<dim3(BSZ, NHEAD, (NQ + 63) / 64), 256, 0, stream>>>(cqk, cv, sraw);
  // 5. out_sa projection
  gemm_kernel<64, 64, 16, 4, 4, false, false><<<dim3((ROWS + 63) / 64, 4), 256, 0, stream>>>(
      sraw, osw, osb, proj, ROWS, 256, DIM, nullptr, 0);
  // 6. tgt2 = LN(tgt + sa), q2 = tgt2 + query_mask
  resid_ln_kernel<<<ROWS, 256, 0, stream>>>(proj, tgt, n2g, n2b, qmask, tgt2, q2);
  // 7. value projection (masked)
  gemm_kernel<128, 128, 16, 8, 8, false, true><<<dim3((Mv + 127) / 128, 2), 256, 0, stream>>>(
      memory, vw, vbi, value, Mv, 256, DIM, kpmask, S);
  // 8. offsets projection (N=512)
  gemm_kernel<64, 64, 16, 4, 4, false, false><<<dim3((ROWS + 63) / 64, 8), 256, 0, stream>>>(
      q2, ow, ob, cqk, ROWS, 512, DIM, nullptr, 0);
  // 9. attention-weight logits (N=256)
  gemm_kernel<64, 64, 16, 4, 4, false, false><<<dim3((ROWS + 63) / 64, 4), 256, 0, stream>>>(
      q2, aww, awb, cv, ROWS, 256, DIM, nullptr, 0);
  // 10. deformable sampling (softmax fused)
  deform_kernel<<<ROWS, 256, 0, stream>>>(value, cqk, cv, bbox, spatial, lstart, sraw, S);
  // 11. out_ca projection
  gemm_kernel<64, 64, 16, 4, 4, false, false><<<dim3((ROWS + 63) / 64, 4), 256, 0, stream>>>(
      sraw, ocw, ocb, proj, ROWS, 256, DIM, nullptr, 0);
  // 12. tgt3 = LN(tgt2 + ca)
  resid_ln_kernel<<<ROWS, 256, 0, stream>>>(proj, tgt2, n1g, n1b, nullptr, tgt3, nullptr);
  // 13. FFN lin1 + relu (N=1024)
  gemm_kernel<64, 64, 16, 4, 4, true, false><<<dim3((ROWS + 63) / 64, 16), 256, 0, stream>>>(
      tgt3, l1w, l1b, ffn1, ROWS, 1024, DIM, nullptr, 0);
  // 14. FFN lin2 (K=1024)
  gemm_kernel<64, 64, 16, 4, 4, false, false><<<dim3((ROWS + 63) / 64, 4), 256, 0, stream>>>(
      ffn1, l2w, l2b, proj, ROWS, 256, 1024, nullptr, 0);
  // 15. out = LN(tgt3 + ffn)
  resid_ln_kernel<<<ROWS, 256, 0, stream>>>(proj, tgt3, n3g, n3b, nullptr, out, nullptr);
}

// Round 2
// 495.156 us; speedup vs baseline: 1.4601x; 1.4601x over previous
//
#include <hip/hip_runtime.h>
#include <hip/hip_bf16.h>
#include <math.h>

#define NQ 300
#define BSZ 8
#define DIM 256
#define NHEAD 8
#define ROWS (NQ * BSZ)  // 2400

typedef __attribute__((ext_vector_type(8))) short bf16x8;
typedef __attribute__((ext_vector_type(4))) float f32x4;

__device__ inline short f2bf(float f) {
  __hip_bfloat16 h = __float2bfloat16(f);
  return *reinterpret_cast<short*>(&h);
}
__device__ inline float bf2f(unsigned short u) {
  union { unsigned u; float f; } c;
  c.u = ((unsigned)u) << 16;
  return c.f;
}

// ---------------- elementwise add (float4) ----------------
__global__ __launch_bounds__(256) void add4_kernel(const float4* __restrict__ a,
                                                   const float4* __restrict__ b,
                                                   float4* __restrict__ o, int n4) {
  int i = blockIdx.x * 256 + threadIdx.x;
  if (i < n4) {
    float4 x = a[i], y = b[i];
    o[i] = make_float4(x.x + y.x, x.y + y.y, x.z + y.z, x.w + y.w);
  }
}

// ---------------- fp32 -> bf16 LDS staging with XOR swizzle ----------------
// Tile: TR rows x 64 K of bf16 (row stride 128 B). slot = 16B = 8 bf16.
// swizzle: byte ^= (row&7)<<4  (applied identically on read side)
template <int TR>
__device__ inline void stage_tile(const float* __restrict__ g, int row0, int rmax,
                                  int stride, int k0, char* lds, int tid) {
#pragma unroll
  for (int p = 0; p < TR / 32; ++p) {
    int row = p * 32 + (tid >> 3);
    int slot = tid & 7;
    float4 v0 = make_float4(0.f, 0.f, 0.f, 0.f), v1 = v0;
    int gr = row0 + row;
    if (gr < rmax) {
      const float* s = g + (size_t)gr * stride + k0 + slot * 8;
      v0 = *(const float4*)s;
      v1 = *(const float4*)(s + 4);
    }
    bf16x8 o;
    o[0] = f2bf(v0.x); o[1] = f2bf(v0.y); o[2] = f2bf(v0.z); o[3] = f2bf(v0.w);
    o[4] = f2bf(v1.x); o[5] = f2bf(v1.y); o[6] = f2bf(v1.z); o[7] = f2bf(v1.w);
    int byte = row * 128 + slot * 16;
    byte ^= (row & 7) << 4;
    *(bf16x8*)(lds + byte) = o;
  }
}

// ---------------- bf16 MFMA GEMM: C[M][N] = A[M][K] @ W[N][K]^T + bias ----------------
// fp32 inputs converted to bf16 in staging; fp32 accumulate (MFMA).
// 256 threads = 4 waves in a 2x2 grid; each wave owns a (BM/2)x(BN/2) sub-tile.
// mfma_f32_16x16x32_bf16: A/B frag: row(M)/col(N)=lane&15, k=(lane>>4)*8+i (8 contig bf16);
// C/D: col=lane&15, row=(lane>>4)*4+reg   [m89-verified]
template <int BM, int BN, bool RELU, bool VMASK, bool OBF16>
__global__ __launch_bounds__(256) void mgemm_kernel(const float* __restrict__ A,
                                                    const float* __restrict__ W,
                                                    const float* __restrict__ bias,
                                                    void* __restrict__ C, int M, int N, int K,
                                                    const unsigned char* __restrict__ vmask,
                                                    int Srows) {
  constexpr int WMT = BM / 2, WNT = BN / 2;
  constexpr int AM = WMT / 16, BF = WNT / 16;
  __shared__ char lds[(BM + BN) * 128];
  char* As = lds;
  char* Bs = lds + BM * 128;
  const int tid = threadIdx.x;
  const int lane = tid & 63;
  const int wid = tid >> 6;
  const int wr = wid >> 1, wc = wid & 1;
  const int m0 = blockIdx.x * BM, n0 = blockIdx.y * BN;

  f32x4 acc[AM][BF];
#pragma unroll
  for (int i = 0; i < AM; ++i)
#pragma unroll
    for (int j = 0; j < BF; ++j) acc[i][j] = {0.f, 0.f, 0.f, 0.f};

  const int arow0 = wr * WMT + (lane & 15);
  const int brow0 = wc * WNT + (lane & 15);
  const int lslot = (lane >> 4) * 16;  // byte offset of this lane's k-octet

  for (int k0 = 0; k0 < K; k0 += 64) {
    __syncthreads();
    stage_tile<BM>(A, m0, M, K, k0, As, tid);
    stage_tile<BN>(W, n0, N, K, k0, Bs, tid);
    __syncthreads();
#pragma unroll
    for (int kk = 0; kk < 2; ++kk) {
      bf16x8 af[AM], bfr[BF];
#pragma unroll
      for (int i = 0; i < AM; ++i) {
        int row = arow0 + i * 16;
        int byte = row * 128 + kk * 64 + lslot;
        byte ^= (row & 7) << 4;
        af[i] = *(bf16x8*)(As + byte);
      }
#pragma unroll
      for (int j = 0; j < BF; ++j) {
        int row = brow0 + j * 16;
        int byte = row * 128 + kk * 64 + lslot;
        byte ^= (row & 7) << 4;
        bfr[j] = *(bf16x8*)(Bs + byte);
      }
#pragma unroll
      for (int i = 0; i < AM; ++i)
#pragma unroll
        for (int j = 0; j < BF; ++j)
          acc[i][j] = __builtin_amdgcn_mfma_f32_16x16x32_bf16(af[i], bfr[j], acc[i][j], 0, 0, 0);
    }
  }

  const int colbase = n0 + wc * WNT + (lane & 15);
  const int rowq = (lane >> 4) * 4;
#pragma unroll
  for (int i = 0; i < AM; ++i) {
#pragma unroll
    for (int r = 0; r < 4; ++r) {
      int grow = m0 + wr * WMT + i * 16 + rowq + r;
      if (grow >= M) continue;
      float mfac = 1.f;
      if (VMASK) mfac = vmask[(size_t)(grow & 7) * Srows + (grow >> 3)] ? 0.f : 1.f;
#pragma unroll
      for (int j = 0; j < BF; ++j) {
        int col = colbase + j * 16;
        float v = acc[i][j][r] + bias[col];
        if (VMASK) v *= mfac;
        if (RELU) v = fmaxf(v, 0.f);
        if (OBF16)
          ((__hip_bfloat16*)C)[(size_t)grow * N + col] = __float2bfloat16(v);
        else
          ((float*)C)[(size_t)grow * N + col] = v;
      }
    }
  }
}

// ---------------- self-attention, flash-style (fp32, unchanged) ----------------
__global__ __launch_bounds__(256) void attn_kernel(const float* __restrict__ cqk,
                                                   const float* __restrict__ cv,
                                                   float* __restrict__ out) {
  __shared__ float Ks[NQ][32];
  __shared__ float Vs[NQ][32];
  const int b = blockIdx.x, h = blockIdx.y, qt = blockIdx.z;
  const int tid = threadIdx.x;
  for (int i = tid; i < NQ * 8; i += 256) {
    int qi = i >> 3, c4 = (i & 7) * 4;
    *(float4*)&Ks[qi][c4] = *(const float4*)&cqk[((size_t)(qi * 8 + b)) * 512 + 256 + h * 32 + c4];
    *(float4*)&Vs[qi][c4] = *(const float4*)&cv[((size_t)(qi * 8 + b)) * 256 + h * 32 + c4];
  }
  __syncthreads();
  const int row = qt * 64 + (tid >> 2);
  const int qr = tid & 3;
  if (row >= NQ) return;
  float qv[8];
  const float* qptr = &cqk[((size_t)(row * 8 + b)) * 512 + h * 32 + qr * 8];
  *(float4*)&qv[0] = *(const float4*)&qptr[0];
  *(float4*)&qv[4] = *(const float4*)&qptr[4];
  const float scale = 0.17677669529663687f;
  float m = -3.0e38f, l = 0.f;
  float acc[8] = {0.f, 0.f, 0.f, 0.f, 0.f, 0.f, 0.f, 0.f};
  for (int k = 0; k < NQ; ++k) {
    const float* kr = &Ks[k][qr * 8];
    float p = 0.f;
#pragma unroll
    for (int j = 0; j < 8; ++j) p = fmaf(qv[j], kr[j], p);
    p += __shfl_xor(p, 1, 4);
    p += __shfl_xor(p, 2, 4);
    float s = p * scale;
    float mn = fmaxf(m, s);
    float corr = __expf(m - mn);
    float e = __expf(s - mn);
    l = l * corr + e;
    const float* vr = &Vs[k][qr * 8];
#pragma unroll
    for (int j = 0; j < 8; ++j) acc[j] = fmaf(acc[j], corr, e * vr[j]);
    m = mn;
  }
  float inv = 1.f / l;
  float* op = &out[((size_t)(row * 8 + b)) * 256 + h * 32 + qr * 8];
#pragma unroll
  for (int j = 0; j < 8; ++j) op[j] = acc[j] * inv;
}

// ---------------- residual + layernorm ----------------
__global__ __launch_bounds__(256) void resid_ln_kernel(const float* __restrict__ X,
                                                       const float* __restrict__ R,
                                                       const float* __restrict__ g,
                                                       const float* __restrict__ be,
                                                       const float* __restrict__ addmask,
                                                       float* __restrict__ out,
                                                       float* __restrict__ out2) {
  const int r = blockIdx.x, c = threadIdx.x;
  const size_t i = (size_t)r * 256 + c;
  float x = X[i] + R[i];
  float s = x;
#pragma unroll
  for (int o = 32; o; o >>= 1) s += __shfl_xor(s, o, 64);
  __shared__ float sm[4], sv[4];
  const int w = c >> 6;
  if ((c & 63) == 0) sm[w] = s;
  __syncthreads();
  float mu = (sm[0] + sm[1] + sm[2] + sm[3]) * (1.f / 256.f);
  float d = x - mu;
  float v = d * d;
#pragma unroll
  for (int o = 32; o; o >>= 1) v += __shfl_xor(v, o, 64);
  if ((c & 63) == 0) sv[w] = v;
  __syncthreads();
  float var = (sv[0] + sv[1] + sv[2] + sv[3]) * (1.f / 256.f);
  float y = d * (1.f / sqrtf(var + 1e-5f)) * g[c] + be[c];
  out[i] = y;
  if (out2) out2[i] = y + addmask[i];
}

// ---------------- multi-scale deformable sampling (value in bf16) ----------------
__global__ __launch_bounds__(256) void deform_kernel(const unsigned short* __restrict__ value,
                                                     const float* __restrict__ off,
                                                     const float* __restrict__ awl,
                                                     const float* __restrict__ bbox,
                                                     const int* __restrict__ spatial,
                                                     const int* __restrict__ lstart,
                                                     float* __restrict__ out, int S) {
  __shared__ int sH[4], sW[4], sL[4];
  __shared__ float sbb[4];
  const int r = blockIdx.x;  // q*8+b
  const int b = r & 7;
  const int tid = threadIdx.x;
  if (tid < 4) {
    sH[tid] = spatial[tid * 2];
    sW[tid] = spatial[tid * 2 + 1];
    sL[tid] = lstart[tid];
    sbb[tid] = bbox[(size_t)r * 4 + tid];
  }
  __syncthreads();
  const float cx = sbb[0], cy = sbb[1], bw = sbb[2], bh = sbb[3];
  float ox = off[(size_t)r * 512 + (size_t)tid * 2];
  float oy = off[(size_t)r * 512 + (size_t)tid * 2 + 1];
  float a = awl[(size_t)r * 256 + tid];
  float mx = a;
#pragma unroll
  for (int o = 16; o; o >>= 1) mx = fmaxf(mx, __shfl_xor(mx, o, 32));
  float e = __expf(a - mx);
  float ssum = e;
#pragma unroll
  for (int o = 16; o; o >>= 1) ssum += __shfl_xor(ssum, o, 32);
  float myaw = e / ssum;

  float acc = 0.f;
  const size_t vb = (size_t)b * 256 + (size_t)tid;
  for (int lp = 0; lp < 32; ++lp) {
    const int l = lp >> 3;
    float bx = __shfl(ox, lp, 32);
    float by = __shfl(oy, lp, 32);
    float alp = __shfl(myaw, lp, 32);
    const float Wf = (float)sW[l], Hf = (float)sH[l];
    const int ls = sL[l], Wi = sW[l];
    float lx = cx + bx * 0.0625f * bw;
    float ly = cy + by * 0.0625f * bh;
    float x = lx * Wf - 0.5f;
    float y = ly * Hf - 0.5f;
    float x0 = floorf(x), y0 = floorf(y);
    float fx = x - x0, fy = y - y0;
    float tap = 0.f;
#pragma unroll
    for (int t = 0; t < 4; ++t) {
      float xi = x0 + (float)(t & 1);
      float yi = y0 + (float)(t >> 1);
      if (xi >= 0.f && yi >= 0.f && xi < Wf && yi < Hf) {
        float wx = (t & 1) ? fx : (1.f - fx);
        float wy = (t >> 1) ? fy : (1.f - fy);
        int idx = ls + (int)yi * Wi + (int)xi;
        tap = fmaf(wx * wy, bf2f(value[(size_t)idx * 2048 + vb]), tap);
      }
    }
    acc = fmaf(alp, tap, acc);
  }
  out[(size_t)r * 256 + tid] = acc;
}

extern "C" void kernel_launch(void* const* d_in, const int* in_sizes, int n_in, void* d_out,
                              int out_size, void* d_ws, size_t ws_size, hipStream_t stream) {
  (void)n_in; (void)out_size; (void)ws_size;
  const float* tgt = (const float*)d_in[0];
  const float* qmask = (const float*)d_in[1];
  const float* bbox = (const float*)d_in[2];
  const float* memory = (const float*)d_in[4];
  const float* ipw = (const float*)d_in[5];
  const float* ipb = (const float*)d_in[6];
  const float* osw = (const float*)d_in[7];
  const float* osb = (const float*)d_in[8];
  const float* n2g = (const float*)d_in[9];
  const float* n2b = (const float*)d_in[10];
  const float* vw = (const float*)d_in[11];
  const float* vbi = (const float*)d_in[12];
  const float* ow = (const float*)d_in[13];
  const float* ob = (const float*)d_in[14];
  const float* aww = (const float*)d_in[15];
  const float* awb = (const float*)d_in[16];
  const float* ocw = (const float*)d_in[17];
  const float* ocb = (const float*)d_in[18];
  const float* n1g = (const float*)d_in[19];
  const float* n1b = (const float*)d_in[20];
  const float* l1w = (const float*)d_in[21];
  const float* l1b = (const float*)d_in[22];
  const float* l2w = (const float*)d_in[23];
  const float* l2b = (const float*)d_in[24];
  const float* n3g = (const float*)d_in[25];
  const float* n3b = (const float*)d_in[26];
  const unsigned char* kpmask = (const unsigned char*)d_in[27];
  const int* spatial = (const int*)d_in[28];
  const int* lstart = (const int*)d_in[29];
  float* out = (float*)d_out;

  const int S = in_sizes[4] / (BSZ * DIM);  // 13294
  const int Mv = S * BSZ;                   // 106352

  float* ws = (float*)d_ws;
  size_t o = 0;
  unsigned short* value = (unsigned short*)(ws + o); o += (size_t)Mv * DIM / 2;  // bf16
  float* qsum = ws + o; o += (size_t)ROWS * DIM;
  float* cqk = ws + o; o += (size_t)ROWS * 512;
  float* cv = ws + o; o += (size_t)ROWS * DIM;
  float* sraw = ws + o; o += (size_t)ROWS * DIM;
  float* proj = ws + o; o += (size_t)ROWS * DIM;
  float* tgt2 = ws + o; o += (size_t)ROWS * DIM;
  float* q2 = ws + o; o += (size_t)ROWS * DIM;
  float* tgt3 = ws + o; o += (size_t)ROWS * DIM;
  float* ffn1 = ws + o; o += (size_t)ROWS * 1024;

  const int MB = (ROWS + 63) / 64;  // 38

  // 1. qsum = tgt + query_mask
  add4_kernel<<<dim3((ROWS * DIM / 4 + 255) / 256), 256, 0, stream>>>(
      (const float4*)tgt, (const float4*)qmask, (float4*)qsum, ROWS * DIM / 4);
  // 2. q/k projection (N=512)
  mgemm_kernel<64, 64, false, false, false><<<dim3(MB, 8), 256, 0, stream>>>(
      qsum, ipw, ipb, cqk, ROWS, 512, DIM, nullptr, 0);
  // 3. v projection
  mgemm_kernel<64, 64, false, false, false><<<dim3(MB, 4), 256, 0, stream>>>(
      tgt, ipw + 512 * DIM, ipb + 512, cv, ROWS, 256, DIM, nullptr, 0);
  // 4. self-attention
  attn_kernel<<<dim3(BSZ, NHEAD, (NQ + 63) / 64), 256, 0, stream>>>(cqk, cv, sraw);
  // 5. out_sa projection
  mgemm_kernel<64, 64, false, false, false><<<dim3(MB, 4), 256, 0, stream>>>(
      sraw, osw, osb, proj, ROWS, 256, DIM, nullptr, 0);
  // 6. tgt2 = LN(tgt + sa), q2 = tgt2 + query_mask
  resid_ln_kernel<<<ROWS, 256, 0, stream>>>(proj, tgt, n2g, n2b, qmask, tgt2, q2);
  // 7. value projection (masked, bf16 out)
  mgemm_kernel<128, 128, false, true, true><<<dim3((Mv + 127) / 128, 2), 256, 0, stream>>>(
      memory, vw, vbi, value, Mv, 256, DIM, kpmask, S);
  // 8. offsets projection (N=512)
  mgemm_kernel<64, 64, false, false, false><<<dim3(MB, 8), 256, 0, stream>>>(
      q2, ow, ob, cqk, ROWS, 512, DIM, nullptr, 0);
  // 9. attention-weight logits (N=256)
  mgemm_kernel<64, 64, false, false, false><<<dim3(MB, 4), 256, 0, stream>>>(
      q2, aww, awb, cv, ROWS, 256, DIM, nullptr, 0);
  // 10. deformable sampling
  deform_kernel<<<ROWS, 256, 0, stream>>>(value, cqk, cv, bbox, spatial, lstart, sraw, S);
  // 11. out_ca projection
  mgemm_kernel<64, 64, false, false, false><<<dim3(MB, 4), 256, 0, stream>>>(
      sraw, ocw, ocb, proj, ROWS, 256, DIM, nullptr, 0);
  // 12. tgt3 = LN(tgt2 + ca)
  resid_ln_kernel<<<ROWS, 256, 0, stream>>>(proj, tgt2, n1g, n1b, nullptr, tgt3, nullptr);
  // 13. FFN lin1 + relu (N=1024)
  mgemm_kernel<64, 64, true, false, false><<<dim3(MB, 16), 256, 0, stream>>>(
      tgt3, l1w, l1b, ffn1, ROWS, 1024, DIM, nullptr, 0);
  // 14. FFN lin2 (K=1024)
  mgemm_kernel<64, 64, false, false, false><<<dim3(MB, 4), 256, 0, stream>>>(
      ffn1, l2w, l2b, proj, ROWS, 256, 1024, nullptr, 0);
  // 15. out = LN(tgt3 + ffn)
  resid_ln_kernel<<<ROWS, 256, 0, stream>>>(proj, tgt3, n3g, n3b, nullptr, out, nullptr);
}